// Round 4
// baseline (181.938 us; speedup 1.0000x reference)
//
#include <hip/hip_runtime.h>
#include <hip/hip_bf16.h>

#define NROWS 16384
#define KDIM  512
#define EDIM  256
#define BM    32
#define BK    64

typedef __attribute__((ext_vector_type(8))) short  short8;
typedef __attribute__((ext_vector_type(4))) float  floatx4;
typedef __attribute__((ext_vector_type(4))) unsigned short ushort4_t;

// fp32 -> bf16 round-to-nearest-even (bit trick; data has no NaN/Inf)
static __device__ __forceinline__ unsigned short f2bf(float f) {
    union { float f; unsigned int u; } v; v.f = f;
    return (unsigned short)((v.u + 0x7FFFu + ((v.u >> 16) & 1u)) >> 16);
}

// ---------------------------------------------------------------------------
// Fused kernel, 2 blocks/CU (grid=512, BM=32, 72 KB LDS total).
// Phase R (rowsum): wave w streams adj rows [m0+4w, m0+4w+4), nontemporal,
//                   wave-shuffle reduce -> dsc[].
// Phase G (GEMM):   bf16 MFMA, tile 32(M) x 256(N full), BK=64, 8 waves in
//                   1x8 grid; wave = 32x32 = 2x2 fragments of 16x16x32.
//                   XOR-swizzled LDS tiles -> conflict-free ds_read_b128.
// Blocks with bit 8 set run G before R: under round-robin XCD dispatch the
// same-CU partner of block i is i+256, so one block streams adj (HBM-bound)
// while the other runs the latency-bound GEMM -> no exposed GEMM tail.
// ---------------------------------------------------------------------------
__global__ __launch_bounds__(512, 4) void fused_kernel(const float* __restrict__ adj,
                                                       const float* __restrict__ x,
                                                       const float* __restrict__ W,
                                                       float* __restrict__ out) {
    __shared__ unsigned short As[BM * BK];     // x tile, bf16, swizzled (4 KB)
    __shared__ unsigned short Bs[EDIM * BK];   // W tile, bf16, swizzled (32 KB)
    __shared__ float dsc[BM];

    const int m0 = blockIdx.x * BM;
    const int t  = threadIdx.x;
    const int l  = t & 63;
    const int w  = t >> 6;       // wave 0..7
    const int lr = l & 15;       // fragment row/col index
    const int lh = l >> 4;       // k-group

    floatx4 acc[2][2] = {};

    // ---------------- phase R: rowsums -> dsc ----------------
    auto rowsum_phase = [&]() {
        const floatx4* p = (const floatx4*)(adj + (size_t)(m0 + w * 4) * NROWS);
#pragma unroll
        for (int rr = 0; rr < 4; ++rr) {
            const floatx4* q = p + (size_t)rr * (NROWS / 4);
            float s0 = 0.f, s1 = 0.f, s2 = 0.f, s3 = 0.f;
#pragma unroll 4
            for (int i = 0; i < 64; i += 4) {
                floatx4 v0 = __builtin_nontemporal_load(&q[l + (i + 0) * 64]);
                floatx4 v1 = __builtin_nontemporal_load(&q[l + (i + 1) * 64]);
                floatx4 v2 = __builtin_nontemporal_load(&q[l + (i + 2) * 64]);
                floatx4 v3 = __builtin_nontemporal_load(&q[l + (i + 3) * 64]);
                s0 += (v0.x + v0.y) + (v0.z + v0.w);
                s1 += (v1.x + v1.y) + (v1.z + v1.w);
                s2 += (v2.x + v2.y) + (v2.z + v2.w);
                s3 += (v3.x + v3.y) + (v3.z + v3.w);
            }
            float s = (s0 + s1) + (s2 + s3);
#pragma unroll
            for (int off = 32; off > 0; off >>= 1)
                s += __shfl_down(s, off, 64);
            if (l == 0) dsc[w * 4 + rr] = 1.0f / (s + 1.0f) + 1.0f;
        }
    };

    // ---------------- phase G: GEMM accumulate ----------------
    auto gemm_phase = [&]() {
        for (int k0 = 0; k0 < KDIM; k0 += BK) {
            if (k0) __syncthreads();

            // stage A: 32 rows x 64 k, fp32 -> bf16 (one pass, 512 threads)
            {
                const int kq = (t & 15) * 4;
                const int r  = t >> 4;           // 0..31
                floatx4 v = __builtin_nontemporal_load(
                    (const floatx4*)(x + (size_t)(m0 + r) * KDIM + k0 + kq));
                ushort4_t o = { f2bf(v.x), f2bf(v.y), f2bf(v.z), f2bf(v.w) };
                const int idx = (r * BK + kq) ^ ((r & 7) << 3);
                *(ushort4_t*)&As[idx] = o;
            }
            // stage B: 256 rows x 64 k, fp32 -> bf16 (8 passes)
            {
                const int kq = (t & 15) * 4;
                int n = t >> 4;                  // 0..31
#pragma unroll 2
                for (int p = 0; p < 8; ++p, n += 32) {
                    float4 v = *(const float4*)(W + (size_t)n * KDIM + k0 + kq);
                    ushort4_t o = { f2bf(v.x), f2bf(v.y), f2bf(v.z), f2bf(v.w) };
                    const int idx = (n * BK + kq) ^ ((n & 7) << 3);
                    *(ushort4_t*)&Bs[idx] = o;
                }
            }
            __syncthreads();

            // compute: 2 k-chunks of 32, 4 MFMA each
#pragma unroll
            for (int kc = 0; kc < 2; ++kc) {
                const int kk = kc * 32 + lh * 8;
                short8 a[2], b[2];
#pragma unroll
                for (int mf = 0; mf < 2; ++mf) {
                    const int r = mf * 16 + lr;
                    a[mf] = *(const short8*)&As[(r * BK + kk) ^ ((r & 7) << 3)];
                }
#pragma unroll
                for (int nf = 0; nf < 2; ++nf) {
                    const int n = w * 32 + nf * 16 + lr;
                    b[nf] = *(const short8*)&Bs[(n * BK + kk) ^ ((n & 7) << 3)];
                }
#pragma unroll
                for (int mf = 0; mf < 2; ++mf)
#pragma unroll
                    for (int nf = 0; nf < 2; ++nf)
                        acc[mf][nf] = __builtin_amdgcn_mfma_f32_16x16x32_bf16(
                            a[mf], b[nf], acc[mf][nf], 0, 0, 0);
            }
        }
    };

    if ((blockIdx.x >> 8) & 1) {
        gemm_phase();
        rowsum_phase();
        __syncthreads();          // dsc visible to all waves before epilogue
    } else {
        rowsum_phase();           // dsc written; barriers inside gemm publish it
        gemm_phase();
    }

    // ---------------- epilogue: d-scale + relu ----------------
    // C/D layout (m89-verified): col = lane&15, row = (lane>>4)*4 + reg
#pragma unroll
    for (int mf = 0; mf < 2; ++mf) {
#pragma unroll
        for (int j = 0; j < 4; ++j) {
            const int rloc = mf * 16 + lh * 4 + j;
            const float dscale = dsc[rloc];
            const size_t row = m0 + rloc;
#pragma unroll
            for (int nf = 0; nf < 2; ++nf) {
                const int col = w * 32 + nf * 16 + lr;
                __builtin_nontemporal_store(fmaxf(acc[mf][nf][j] * dscale, 0.f),
                                            &out[row * EDIM + col]);
            }
        }
    }
}

extern "C" void kernel_launch(void* const* d_in, const int* in_sizes, int n_in,
                              void* d_out, int out_size, void* d_ws, size_t ws_size,
                              hipStream_t stream) {
    const float* adj = (const float*)d_in[0];   // [16384, 16384] fp32
    const float* x   = (const float*)d_in[1];   // [16384, 512]   fp32
    const float* W   = (const float*)d_in[2];   // [256, 512]     fp32
    float* out = (float*)d_out;                 // [16384, 256]   fp32

    fused_kernel<<<NROWS / BM, 512, 0, stream>>>(adj, x, W, out);
}

// Round 5
// 180.237 us; speedup vs baseline: 1.0094x; 1.0094x over previous
//
#include <hip/hip_runtime.h>
#include <hip/hip_bf16.h>

#define NROWS 16384
#define KDIM  512
#define EDIM  256
#define BM    64
#define BK    64

typedef __attribute__((ext_vector_type(8))) short  short8;
typedef __attribute__((ext_vector_type(4))) float  floatx4;
typedef __attribute__((ext_vector_type(4))) unsigned short ushort4_t;

// fp32 -> bf16 round-to-nearest-even (bit trick; data has no NaN/Inf)
static __device__ __forceinline__ unsigned short f2bf(float f) {
    union { float f; unsigned int u; } v; v.f = f;
    return (unsigned short)((v.u + 0x7FFFu + ((v.u >> 16) & 1u)) >> 16);
}

// ---------------------------------------------------------------------------
// Fused kernel: one block per 64 output rows (grid=256 = 1 block/CU).
// Phase 1: wave w (of 8) streams adj rows [m0+8w, m0+8w+8) (64 KB each,
//          nontemporal), wave-shuffle reduce -> dsc[] in LDS.
// Phase 2: bf16 MFMA GEMM, block tile 64(M) x 256(N=full), BK=64,
//          8 waves in 2(M) x 4(N) grid, wave = 32x64 = 2x4 fragments of
//          16x16x32. A (x) and B (W) converted fp32->bf16 during staging.
//          LDS tiles XOR-swizzled so stride-128B ds_read_b128 is conflict-free.
// Epilogue: d-scale + relu, nontemporal stores.
// Measured (round 2 structure): 178.2 us = 6.31 TB/s effective on the
// mandatory 1.124 GB -> at the m13 streaming ceiling.
// ---------------------------------------------------------------------------
__global__ __launch_bounds__(512) void fused_kernel(const float* __restrict__ adj,
                                                    const float* __restrict__ x,
                                                    const float* __restrict__ W,
                                                    float* __restrict__ out) {
    __shared__ unsigned short As[BM * BK];     // x tile, bf16, swizzled (8 KB)
    __shared__ unsigned short Bs[EDIM * BK];   // W tile, bf16, swizzled (32 KB)
    __shared__ float dsc[BM];

    const int m0 = blockIdx.x * BM;
    const int t  = threadIdx.x;
    const int l  = t & 63;
    const int w  = t >> 6;       // wave 0..7

    // ---------------- phase 1: rowsums -> dsc ----------------
    {
        const floatx4* p = (const floatx4*)(adj + (size_t)(m0 + w * 8) * NROWS);
#pragma unroll
        for (int rr = 0; rr < 8; ++rr) {
            const floatx4* q = p + (size_t)rr * (NROWS / 4);
            float s0 = 0.f, s1 = 0.f, s2 = 0.f, s3 = 0.f;
#pragma unroll 4
            for (int i = 0; i < 64; i += 4) {
                floatx4 v0 = __builtin_nontemporal_load(&q[l + (i + 0) * 64]);
                floatx4 v1 = __builtin_nontemporal_load(&q[l + (i + 1) * 64]);
                floatx4 v2 = __builtin_nontemporal_load(&q[l + (i + 2) * 64]);
                floatx4 v3 = __builtin_nontemporal_load(&q[l + (i + 3) * 64]);
                s0 += (v0.x + v0.y) + (v0.z + v0.w);
                s1 += (v1.x + v1.y) + (v1.z + v1.w);
                s2 += (v2.x + v2.y) + (v2.z + v2.w);
                s3 += (v3.x + v3.y) + (v3.z + v3.w);
            }
            float s = (s0 + s1) + (s2 + s3);
#pragma unroll
            for (int off = 32; off > 0; off >>= 1)
                s += __shfl_down(s, off, 64);
            if (l == 0) dsc[w * 8 + rr] = 1.0f / (s + 1.0f) + 1.0f;
        }
    }

    // ---------------- phase 2: GEMM ----------------
    const int lr = l & 15;       // fragment row/col index
    const int lh = l >> 4;       // k-group
    const int wm = w >> 2;       // 0..1  (M half)
    const int wn = w & 3;        // 0..3  (N quarter)

    floatx4 acc[2][4] = {};

    for (int k0 = 0; k0 < KDIM; k0 += BK) {
        if (k0) __syncthreads();

        // --- stage A: 64 rows x 64 k, fp32 -> bf16 (2 passes, nontemporal) ---
        {
            const int kq = (t & 15) * 4;   // k offset (floats), multiple of 4
            int r = t >> 4;                // 0..31
#pragma unroll
            for (int p = 0; p < 2; ++p, r += 32) {
                floatx4 v = __builtin_nontemporal_load(
                    (const floatx4*)(x + (size_t)(m0 + r) * KDIM + k0 + kq));
                ushort4_t o = { f2bf(v.x), f2bf(v.y), f2bf(v.z), f2bf(v.w) };
                const int idx = (r * BK + kq) ^ ((r & 7) << 3);
                *(ushort4_t*)&As[idx] = o;
            }
        }
        // --- stage B: 256 rows x 64 k, fp32 -> bf16 (8 passes, L2-cached) ---
        {
            const int kq = (t & 15) * 4;
            int n = t >> 4;                // 0..31
#pragma unroll
            for (int p = 0; p < 8; ++p, n += 32) {
                float4 v = *(const float4*)(W + (size_t)n * KDIM + k0 + kq);
                ushort4_t o = { f2bf(v.x), f2bf(v.y), f2bf(v.z), f2bf(v.w) };
                const int idx = (n * BK + kq) ^ ((n & 7) << 3);
                *(ushort4_t*)&Bs[idx] = o;
            }
        }
        __syncthreads();

        // --- compute: 2 k-chunks of 32, 8 MFMA each ---
#pragma unroll
        for (int kc = 0; kc < 2; ++kc) {
            const int kk = kc * 32 + lh * 8;
            short8 a[2], b[4];
#pragma unroll
            for (int mf = 0; mf < 2; ++mf) {
                const int r = wm * 32 + mf * 16 + lr;
                a[mf] = *(const short8*)&As[(r * BK + kk) ^ ((r & 7) << 3)];
            }
#pragma unroll
            for (int nf = 0; nf < 4; ++nf) {
                const int n = wn * 64 + nf * 16 + lr;
                b[nf] = *(const short8*)&Bs[(n * BK + kk) ^ ((n & 7) << 3)];
            }
#pragma unroll
            for (int mf = 0; mf < 2; ++mf)
#pragma unroll
                for (int nf = 0; nf < 4; ++nf)
                    acc[mf][nf] = __builtin_amdgcn_mfma_f32_16x16x32_bf16(
                        a[mf], b[nf], acc[mf][nf], 0, 0, 0);
        }
    }

    // ---------------- epilogue: d-scale + relu, nontemporal stores ----------
    // C/D layout (m89-verified): col = lane&15, row = (lane>>4)*4 + reg
#pragma unroll
    for (int mf = 0; mf < 2; ++mf) {
#pragma unroll
        for (int j = 0; j < 4; ++j) {
            const int rloc = wm * 32 + mf * 16 + lh * 4 + j;
            const float dscale = dsc[rloc];
            const size_t row = m0 + rloc;
#pragma unroll
            for (int nf = 0; nf < 4; ++nf) {
                const int col = wn * 64 + nf * 16 + lr;
                __builtin_nontemporal_store(fmaxf(acc[mf][nf][j] * dscale, 0.f),
                                            &out[row * EDIM + col]);
            }
        }
    }
}

extern "C" void kernel_launch(void* const* d_in, const int* in_sizes, int n_in,
                              void* d_out, int out_size, void* d_ws, size_t ws_size,
                              hipStream_t stream) {
    const float* adj = (const float*)d_in[0];   // [16384, 16384] fp32
    const float* x   = (const float*)d_in[1];   // [16384, 512]   fp32
    const float* W   = (const float*)d_in[2];   // [256, 512]     fp32
    float* out = (float*)d_out;                 // [16384, 256]   fp32

    fused_kernel<<<NROWS / BM, 512, 0, stream>>>(adj, x, W, out);
}

// Round 6
// 178.518 us; speedup vs baseline: 1.0192x; 1.0096x over previous
//
#include <hip/hip_runtime.h>
#include <hip/hip_bf16.h>

#define NROWS 16384
#define KDIM  512
#define EDIM  256
#define BM    64
#define BK    64

typedef __attribute__((ext_vector_type(8))) short  short8;
typedef __attribute__((ext_vector_type(4))) float  floatx4;
typedef __attribute__((ext_vector_type(4))) unsigned short ushort4_t;

// fp32 -> bf16 round-to-nearest-even (bit trick; data has no NaN/Inf)
static __device__ __forceinline__ unsigned short f2bf(float f) {
    union { float f; unsigned int u; } v; v.f = f;
    return (unsigned short)((v.u + 0x7FFFu + ((v.u >> 16) & 1u)) >> 16);
}

// ---------------------------------------------------------------------------
// Fused kernel: one block per 64 output rows (grid=256 = 1 block/CU).
// Phase 1: wave w (of 8) streams adj rows [m0+8w, m0+8w+8) (64 KB each,
//          nontemporal), wave-shuffle reduce -> dsc[] in LDS.
// Phase 2: bf16 MFMA GEMM, block tile 64(M) x 256(N=full), BK=64,
//          8 waves in 2(M) x 4(N) grid, wave = 32x64 = 2x4 fragments of
//          16x16x32. A (x) and B (W) converted fp32->bf16 during staging.
//          LDS tiles XOR-swizzled so stride-128B ds_read_b128 is conflict-free.
// Epilogue: d-scale + relu.
//
// Roofline accounting (measured round 2, this exact source): 178.17 us on
// mandatory 1.124 GB HBM traffic = 6.31 TB/s effective — at the measured
// streaming ceiling (m13: 6.29 TB/s). Rowsum phase = 1.074 GB @ ~6.3;
// GEMM phase duration == its own mandatory x+out traffic @ ~6.3. No
// exposed non-BW tail exists; overlap schemes (R3) and nontemporal x/out
// (R4) both measured neutral-to-negative.
// ---------------------------------------------------------------------------
__global__ __launch_bounds__(512) void fused_kernel(const float* __restrict__ adj,
                                                    const float* __restrict__ x,
                                                    const float* __restrict__ W,
                                                    float* __restrict__ out) {
    __shared__ unsigned short As[BM * BK];     // x tile, bf16, swizzled (8 KB)
    __shared__ unsigned short Bs[EDIM * BK];   // W tile, bf16, swizzled (32 KB)
    __shared__ float dsc[BM];

    const int m0 = blockIdx.x * BM;
    const int t  = threadIdx.x;
    const int l  = t & 63;
    const int w  = t >> 6;       // wave 0..7

    // ---------------- phase 1: rowsums -> dsc ----------------
    {
        const floatx4* p = (const floatx4*)(adj + (size_t)(m0 + w * 8) * NROWS);
#pragma unroll
        for (int rr = 0; rr < 8; ++rr) {
            const floatx4* q = p + (size_t)rr * (NROWS / 4);
            float s0 = 0.f, s1 = 0.f, s2 = 0.f, s3 = 0.f;
#pragma unroll 4
            for (int i = 0; i < 64; i += 4) {
                floatx4 v0 = __builtin_nontemporal_load(&q[l + (i + 0) * 64]);
                floatx4 v1 = __builtin_nontemporal_load(&q[l + (i + 1) * 64]);
                floatx4 v2 = __builtin_nontemporal_load(&q[l + (i + 2) * 64]);
                floatx4 v3 = __builtin_nontemporal_load(&q[l + (i + 3) * 64]);
                s0 += (v0.x + v0.y) + (v0.z + v0.w);
                s1 += (v1.x + v1.y) + (v1.z + v1.w);
                s2 += (v2.x + v2.y) + (v2.z + v2.w);
                s3 += (v3.x + v3.y) + (v3.z + v3.w);
            }
            float s = (s0 + s1) + (s2 + s3);
#pragma unroll
            for (int off = 32; off > 0; off >>= 1)
                s += __shfl_down(s, off, 64);
            if (l == 0) dsc[w * 8 + rr] = 1.0f / (s + 1.0f) + 1.0f;
        }
    }

    // ---------------- phase 2: GEMM ----------------
    const int lr = l & 15;       // fragment row/col index
    const int lh = l >> 4;       // k-group
    const int wm = w >> 2;       // 0..1  (M half)
    const int wn = w & 3;        // 0..3  (N quarter)

    floatx4 acc[2][4] = {};

    for (int k0 = 0; k0 < KDIM; k0 += BK) {
        if (k0) __syncthreads();

        // --- stage A: 64 rows x 64 k, fp32 -> bf16 (2 passes) ---
        {
            const int kq = (t & 15) * 4;   // k offset (floats), multiple of 4
            int r = t >> 4;                // 0..31
#pragma unroll
            for (int p = 0; p < 2; ++p, r += 32) {
                float4 v = *(const float4*)(x + (size_t)(m0 + r) * KDIM + k0 + kq);
                ushort4_t o = { f2bf(v.x), f2bf(v.y), f2bf(v.z), f2bf(v.w) };
                const int idx = (r * BK + kq) ^ ((r & 7) << 3);
                *(ushort4_t*)&As[idx] = o;
            }
        }
        // --- stage B: 256 rows x 64 k, fp32 -> bf16 (8 passes, full tile) ---
        {
            const int kq = (t & 15) * 4;
            int n = t >> 4;                // 0..31
#pragma unroll
            for (int p = 0; p < 8; ++p, n += 32) {
                float4 v = *(const float4*)(W + (size_t)n * KDIM + k0 + kq);
                ushort4_t o = { f2bf(v.x), f2bf(v.y), f2bf(v.z), f2bf(v.w) };
                const int idx = (n * BK + kq) ^ ((n & 7) << 3);
                *(ushort4_t*)&Bs[idx] = o;
            }
        }
        __syncthreads();

        // --- compute: 2 k-chunks of 32, 8 MFMA each ---
#pragma unroll
        for (int kc = 0; kc < 2; ++kc) {
            const int kk = kc * 32 + lh * 8;
            short8 a[2], b[4];
#pragma unroll
            for (int mf = 0; mf < 2; ++mf) {
                const int r = wm * 32 + mf * 16 + lr;
                a[mf] = *(const short8*)&As[(r * BK + kk) ^ ((r & 7) << 3)];
            }
#pragma unroll
            for (int nf = 0; nf < 4; ++nf) {
                const int n = wn * 64 + nf * 16 + lr;
                b[nf] = *(const short8*)&Bs[(n * BK + kk) ^ ((n & 7) << 3)];
            }
#pragma unroll
            for (int mf = 0; mf < 2; ++mf)
#pragma unroll
                for (int nf = 0; nf < 4; ++nf)
                    acc[mf][nf] = __builtin_amdgcn_mfma_f32_16x16x32_bf16(
                        a[mf], b[nf], acc[mf][nf], 0, 0, 0);
        }
    }

    // ---------------- epilogue: d-scale + relu ----------------
    // C/D layout (m89-verified): col = lane&15, row = (lane>>4)*4 + reg
#pragma unroll
    for (int mf = 0; mf < 2; ++mf) {
#pragma unroll
        for (int j = 0; j < 4; ++j) {
            const int rloc = wm * 32 + mf * 16 + lh * 4 + j;
            const float dscale = dsc[rloc];
            const size_t row = m0 + rloc;
#pragma unroll
            for (int nf = 0; nf < 4; ++nf) {
                const int col = wn * 64 + nf * 16 + lr;
                out[row * EDIM + col] = fmaxf(acc[mf][nf][j] * dscale, 0.f);
            }
        }
    }
}

extern "C" void kernel_launch(void* const* d_in, const int* in_sizes, int n_in,
                              void* d_out, int out_size, void* d_ws, size_t ws_size,
                              hipStream_t stream) {
    const float* adj = (const float*)d_in[0];   // [16384, 16384] fp32
    const float* x   = (const float*)d_in[1];   // [16384, 512]   fp32
    const float* W   = (const float*)d_in[2];   // [256, 512]     fp32
    float* out = (float*)d_out;                 // [16384, 256]   fp32

    fused_kernel<<<NROWS / BM, 512, 0, stream>>>(adj, x, W, out);
}